// Round 10
// baseline (1077.914 us; speedup 1.0000x reference)
//
#include <hip/hip_runtime.h>
#include <stdint.h>

// ResRnn: T=128 sequential steps of  h=|s@W1^T+b1|; s'=0.9*shift(s)+0.1*(h@W2^T+b2)
// Persistent kernel: 256 WGs (1/CU), 4 independent batch-groups of 64 WGs,
// bf16 weights resident in VGPRs as MFMA B-frags.
// R6 protocol (proven): per-chunk monotone gen flags, 64B-strided slots,
//     tid0 store AFTER __syncthreads; relaxed agent-scope data stores.
// R14 (1632us): plain global_load_dwordx4 sc1 operand loads (off the TCC
//     atomic pipe) + counted vmcnt pipeline + sched_barrier fences.
// R15 (1068us): K-tiled slab layouts SbT/hbT/SfT[kblk][128row][8] — every
//     LLCLD = fully-used 128B lines, 4 TA segments; epilogue thread-remap
//     makes stores wave-contiguous. MfmaUtil 11.0, VALUBusy 9.7.
// R16 (this round): PIPELINE DEPTH 2 -> 4 (concurrency probe).
//     Effective read BW = 32MB/phase / 4.2us = 7.6TB/s with only ~10-12
//     outstanding 1KB loads/wave — Little's law says we may be
//     CONCURRENCY-limited, not MALL-BW-limited. Issue all 32 LLCLDs per
//     phase up front (4 static buffers xa..xd), drain with counted
//     thresholds = loads-REMAINING-after-block (correct for both the
//     kb==0 wave's 4-asm-load block 0 and the 8-load blocks, via in-order
//     vmcnt retirement): VMW(24/16/8/0), +1 each when prevv's LLCLD is
//     issued last (chunk>=2 branch, WG-uniform).
//     If neutral -> MALL sc1-read ceiling ~7.6TB/s is real; next lever is
//     XCD-local staging. Protocol/flags/stores byte-identical to R15.

#define NSTEPS 128
#define NB 128
#define WID 2048
#define SS 1984   // recurrent state width (WIDTH - INPUT_SIZE)

typedef __attribute__((ext_vector_type(8))) short short8;
typedef __attribute__((ext_vector_type(4))) short short4v;
typedef __attribute__((ext_vector_type(4))) float f32x4;
typedef unsigned long long u64;

static __device__ __forceinline__ short f2bf(float f) {
  union { float f; unsigned u; } v; v.f = f;
  unsigned r = (v.u + 0x7fffu + ((v.u >> 16) & 1u)) >> 16;  // RNE
  return (short)r;
}

static __device__ __forceinline__ short8 pack8(f32x4 lo, f32x4 hi) {
  short8 r;
  r[0] = f2bf(lo[0]); r[1] = f2bf(lo[1]); r[2] = f2bf(lo[2]); r[3] = f2bf(lo[3]);
  r[4] = f2bf(hi[0]); r[5] = f2bf(hi[1]); r[6] = f2bf(hi[2]); r[7] = f2bf(hi[3]);
  return r;
}

// write-through store to the agent coherence point (LLC); does not dirty L2
static __device__ __forceinline__ void ast64(void* p, u64 v) {
  __hip_atomic_store((u64*)p, v, __ATOMIC_RELAXED, __HIP_MEMORY_SCOPE_AGENT);
}
// LLC-direct coherent flag load
static __device__ __forceinline__ unsigned ald32(const unsigned* p) {
  return __hip_atomic_load(p, __ATOMIC_RELAXED, __HIP_MEMORY_SCOPE_AGENT);
}

// plain 16B agent-coherent load (sc1 = bypass stale L1/L2, read MALL).
// NO waitcnt inside — caller MUST fence with VMW() before consuming.
#define LLCLD(d, a) \
  asm volatile("global_load_dwordx4 %0, %1, off sc1" : "=&v"(d) : "v"(a))
// counted vmem wait + scheduler fence (rule #18: stop MFMA hoisting above it)
#define VMW(n) do { \
    asm volatile("s_waitcnt vmcnt(" #n ")" ::: "memory"); \
    __builtin_amdgcn_sched_barrier(0); \
  } while (0)

// ---- phase-1 issue macros (literal b: static reg indexing, rule #20) ----
// Tiled state reads: block b, sub i: slab base = kb/8 + 16b + 4i - 8 (+slabL).
#define P1ISSUE(b, X) do {                                                    \
    if (kb == 0 && (b) == 0) {  /* ks 0,1 = x_t input; ks 2,3 = state slabs 0..7 */ \
      const float* q0_ = inp + ((size_t)t * NB + m0) * 64 + q8;               \
      const float* q1_ = inp + ((size_t)t * NB + m1) * 64 + q8;               \
      X[0] = pack8(*(const f32x4*)q0_, *(const f32x4*)(q0_ + 4));             \
      X[1] = pack8(*(const f32x4*)q1_, *(const f32x4*)(q1_ + 4));             \
      X[2] = pack8(*(const f32x4*)(q0_ + 32), *(const f32x4*)(q0_ + 36));     \
      X[3] = pack8(*(const f32x4*)(q1_ + 32), *(const f32x4*)(q1_ + 36));     \
      const short* s_ = SbOld + (size_t)slabL * 1024;                         \
      LLCLD(X[4], (s_ + rowoff0));           LLCLD(X[5], (s_ + rowoff1));     \
      LLCLD(X[6], (s_ + 4096 + rowoff0));    LLCLD(X[7], (s_ + 4096 + rowoff1)); \
    } else {                                                                  \
      const short* s_ = SbOld + (size_t)(kb / 8 + 16 * (b) - 8 + slabL) * 1024; \
      LLCLD(X[0], (s_ + rowoff0));           LLCLD(X[1], (s_ + rowoff1));     \
      LLCLD(X[2], (s_ + 4096 + rowoff0));    LLCLD(X[3], (s_ + 4096 + rowoff1)); \
      LLCLD(X[4], (s_ + 8192 + rowoff0));    LLCLD(X[5], (s_ + 8192 + rowoff1)); \
      LLCLD(X[6], (s_ + 12288 + rowoff0));   LLCLD(X[7], (s_ + 12288 + rowoff1)); \
    }                                                                         \
  } while (0)

#define P1MFMA(b, X) do {                                                     \
    a00 = __builtin_amdgcn_mfma_f32_16x16x32_bf16(X[0], B1[4*(b)+0][0], a00, 0,0,0); \
    a01 = __builtin_amdgcn_mfma_f32_16x16x32_bf16(X[0], B1[4*(b)+0][1], a01, 0,0,0); \
    a10 = __builtin_amdgcn_mfma_f32_16x16x32_bf16(X[1], B1[4*(b)+0][0], a10, 0,0,0); \
    a11 = __builtin_amdgcn_mfma_f32_16x16x32_bf16(X[1], B1[4*(b)+0][1], a11, 0,0,0); \
    a00 = __builtin_amdgcn_mfma_f32_16x16x32_bf16(X[2], B1[4*(b)+1][0], a00, 0,0,0); \
    a01 = __builtin_amdgcn_mfma_f32_16x16x32_bf16(X[2], B1[4*(b)+1][1], a01, 0,0,0); \
    a10 = __builtin_amdgcn_mfma_f32_16x16x32_bf16(X[3], B1[4*(b)+1][0], a10, 0,0,0); \
    a11 = __builtin_amdgcn_mfma_f32_16x16x32_bf16(X[3], B1[4*(b)+1][1], a11, 0,0,0); \
    a00 = __builtin_amdgcn_mfma_f32_16x16x32_bf16(X[4], B1[4*(b)+2][0], a00, 0,0,0); \
    a01 = __builtin_amdgcn_mfma_f32_16x16x32_bf16(X[4], B1[4*(b)+2][1], a01, 0,0,0); \
    a10 = __builtin_amdgcn_mfma_f32_16x16x32_bf16(X[5], B1[4*(b)+2][0], a10, 0,0,0); \
    a11 = __builtin_amdgcn_mfma_f32_16x16x32_bf16(X[5], B1[4*(b)+2][1], a11, 0,0,0); \
    a00 = __builtin_amdgcn_mfma_f32_16x16x32_bf16(X[6], B1[4*(b)+3][0], a00, 0,0,0); \
    a01 = __builtin_amdgcn_mfma_f32_16x16x32_bf16(X[6], B1[4*(b)+3][1], a01, 0,0,0); \
    a10 = __builtin_amdgcn_mfma_f32_16x16x32_bf16(X[7], B1[4*(b)+3][0], a10, 0,0,0); \
    a11 = __builtin_amdgcn_mfma_f32_16x16x32_bf16(X[7], B1[4*(b)+3][1], a11, 0,0,0); \
  } while (0)

// phase-2 tiled h reads: slab base = kb/8 + 16b + 4i (+slabL)
#define P2ISSUE(b, X) do {                                                    \
    const short* h_ = hb + (size_t)(kb / 8 + 16 * (b) + slabL) * 1024;        \
    LLCLD(X[0], (h_ + rowoff0));           LLCLD(X[1], (h_ + rowoff1));       \
    LLCLD(X[2], (h_ + 4096 + rowoff0));    LLCLD(X[3], (h_ + 4096 + rowoff1)); \
    LLCLD(X[4], (h_ + 8192 + rowoff0));    LLCLD(X[5], (h_ + 8192 + rowoff1)); \
    LLCLD(X[6], (h_ + 12288 + rowoff0));   LLCLD(X[7], (h_ + 12288 + rowoff1)); \
  } while (0)

#define P2MFMA(b, X) do {                                                     \
    c00 = __builtin_amdgcn_mfma_f32_16x16x32_bf16(X[0], B2[4*(b)+0][0], c00, 0,0,0); \
    c01 = __builtin_amdgcn_mfma_f32_16x16x32_bf16(X[0], B2[4*(b)+0][1], c01, 0,0,0); \
    c10 = __builtin_amdgcn_mfma_f32_16x16x32_bf16(X[1], B2[4*(b)+0][0], c10, 0,0,0); \
    c11 = __builtin_amdgcn_mfma_f32_16x16x32_bf16(X[1], B2[4*(b)+0][1], c11, 0,0,0); \
    c00 = __builtin_amdgcn_mfma_f32_16x16x32_bf16(X[2], B2[4*(b)+1][0], c00, 0,0,0); \
    c01 = __builtin_amdgcn_mfma_f32_16x16x32_bf16(X[2], B2[4*(b)+1][1], c01, 0,0,0); \
    c10 = __builtin_amdgcn_mfma_f32_16x16x32_bf16(X[3], B2[4*(b)+1][0], c10, 0,0,0); \
    c11 = __builtin_amdgcn_mfma_f32_16x16x32_bf16(X[3], B2[4*(b)+1][1], c11, 0,0,0); \
    c00 = __builtin_amdgcn_mfma_f32_16x16x32_bf16(X[4], B2[4*(b)+2][0], c00, 0,0,0); \
    c01 = __builtin_amdgcn_mfma_f32_16x16x32_bf16(X[4], B2[4*(b)+2][1], c01, 0,0,0); \
    c10 = __builtin_amdgcn_mfma_f32_16x16x32_bf16(X[5], B2[4*(b)+2][0], c10, 0,0,0); \
    c11 = __builtin_amdgcn_mfma_f32_16x16x32_bf16(X[5], B2[4*(b)+2][1], c11, 0,0,0); \
    c00 = __builtin_amdgcn_mfma_f32_16x16x32_bf16(X[6], B2[4*(b)+3][0], c00, 0,0,0); \
    c01 = __builtin_amdgcn_mfma_f32_16x16x32_bf16(X[6], B2[4*(b)+3][1], c01, 0,0,0); \
    c10 = __builtin_amdgcn_mfma_f32_16x16x32_bf16(X[7], B2[4*(b)+3][0], c10, 0,0,0); \
    c11 = __builtin_amdgcn_mfma_f32_16x16x32_bf16(X[7], B2[4*(b)+3][1], c11, 0,0,0); \
  } while (0)

__global__ __launch_bounds__(256, 1)
void resrnn_kernel(const float* __restrict__ inp, const float* __restrict__ W1,
                   const float* __restrict__ b1f, const float* __restrict__ W2,
                   const float* __restrict__ b2f, float* __restrict__ out,
                   unsigned char* __restrict__ ws)
{
  const int tid   = threadIdx.x;
  const int bid   = blockIdx.x;
  const int group = bid & 3;        // 4 independent batch groups (32 rows each)
  const int chunk = bid >> 2;       // 64 N-chunks of 32 cols
  const int mbase = group * 32;
  const int n0    = chunk * 32;
  const int wave  = tid >> 6;
  const int lane  = tid & 63;
  const int l15   = lane & 15;
  const int q8    = (lane >> 4) * 8;
  const int kb    = wave * 512;     // K split 4 ways across waves
  const int slabL = lane >> 4;      // tiled-read slab offset per lane quad

  // per-group flag arrays: 64 chunks x 64B slots (16 u32 stride), monotone gens
  unsigned* sgen = (unsigned*)(ws + group * 8192);          // S-chunk ready: value t+1
  unsigned* hgen = (unsigned*)(ws + group * 8192 + 4096);   // h-chunk ready: value t+1
  // tiled buffers: SfT[248 kblk][128 row][8] f32 ; SbT[248][128][8] bf16 ;
  // hbT[256][128][8] bf16
  float* Sf0 = (float*)(ws + 32768);                 // fp32 state master, ping
  float* Sf1 = (float*)(ws + 32768 + 1015808);       // pong
  short* Sb0 = (short*)(ws + 32768 + 2031616);       // bf16 state, ping
  short* Sb1 = (short*)(ws + 32768 + 2539520);       // pong
  short* hb  = (short*)(ws + 32768 + 3047424);       // bf16 h buffer (tiled)

  __shared__ float red[4][16][65];  // +1 pad: conflict-free cross-wave reduce

  // ---- one-time: load & convert weight B-fragments into registers ----
  // B-frag layout (verified m89): n = lane&15 (row of W), k = (lane>>4)*8+j contiguous
  short8 B1[16][2], B2[16][2];
#pragma unroll
  for (int ks = 0; ks < 16; ++ks) {
#pragma unroll
    for (int nt = 0; nt < 2; ++nt) {
      const float* p1 = W1 + (size_t)(n0 + nt * 16 + l15) * WID + (kb + ks * 32 + q8);
      B1[ks][nt] = pack8(*(const f32x4*)p1, *(const f32x4*)(p1 + 4));
      const float* p2 = W2 + (size_t)(n0 + nt * 16 + l15) * WID + (kb + ks * 32 + q8);
      B2[ks][nt] = pack8(*(const f32x4*)p2, *(const f32x4*)(p2 + 4));
    }
  }

  const int m0 = mbase + l15;        // A-frag rows (m-tile 0)
  const int m1 = mbase + 16 + l15;   // m-tile 1
  const int rowoff0 = (mbase + l15) * 8;        // shorts/floats into a slab
  const int rowoff1 = rowoff0 + 128;            // +16 rows

  // epilogue thread-remap (bijection over 32 rows x 8 col-quads):
  // ml = (tid&63)>>1, nl = wave*8 + (tid&1)*4 -> wave's stores are contiguous
  const int ml   = (tid & 63) >> 1;
  const int nl   = ((tid >> 6) << 3) + ((tid & 1) << 2);
  const int mrow = mbase + ml;
  const int c0   = n0 + nl;          // this thread's absolute output column
  // tiled store/load offset: slab n0/8+wave, row mrow, elem (tid&1)*4
  const size_t toff = (size_t)(n0 / 8 + wave) * 1024 + (size_t)mrow * 8
                    + (size_t)((tid & 1) << 2);

  // biases for this thread's 4 output columns, loaded once (constant over t)
  const f32x4 b1r = *(const f32x4*)(b1f + c0);
  const f32x4 b2r = *(const f32x4*)(b2f + c0);

  // phase-1 wait setup: lanes 0..15 poll the 16 A-operand producers;
  // lane 16 polls chunk-2 (covers the hoisted fp32 prev read).
  const int p1pc = 16 * wave + l15 - 2;
  const bool p1needA = (lane < 16) && (p1pc >= 0);
  const bool p1needB = (lane == 16) && (chunk >= 2);
  const unsigned* p1fp =
      p1needA ? (sgen + p1pc * 16)
              : (sgen + (chunk >= 2 ? chunk - 2 : 0) * 16);
  // phase-2 wait setup: lanes 0..15 poll h-chunks 16w+l15
  const unsigned* p2fp = hgen + (16 * wave + l15) * 16;

  short8 xa[8], xb[8], xc[8], xd[8];   // 4-deep in-flight operand blocks

#pragma unroll 1
  for (int t = 0; t < NSTEPS; ++t) {
    const float* SfOld = (t & 1) ? Sf1 : Sf0;
    float*       SfNew = (t & 1) ? Sf0 : Sf1;
    const short* SbOld = (t & 1) ? Sb1 : Sb0;
    short*       SbNew = (t & 1) ? Sb0 : Sb1;

    // ================= phase 1: u = s_in @ W1^T ; h = |u + b1| =================
    f32x4 a00{}, a01{}, a10{}, a11{};
    f32x4 prevv;
    if (t == 0) {
      // state is zero: only the x_t part contributes (wave 0, ks 0..1)
      prevv = (c0 < 64) ? *(const f32x4*)(inp + (size_t)mrow * 64 + c0)
                        : f32x4{0.f, 0.f, 0.f, 0.f};
      if (kb == 0) {
        const float* q0_ = inp + (size_t)m0 * 64 + q8;
        const float* q1_ = inp + (size_t)m1 * 64 + q8;
        short8 x0 = pack8(*(const f32x4*)q0_, *(const f32x4*)(q0_ + 4));
        short8 x1 = pack8(*(const f32x4*)q1_, *(const f32x4*)(q1_ + 4));
        short8 x2 = pack8(*(const f32x4*)(q0_ + 32), *(const f32x4*)(q0_ + 36));
        short8 x3 = pack8(*(const f32x4*)(q1_ + 32), *(const f32x4*)(q1_ + 36));
        a00 = __builtin_amdgcn_mfma_f32_16x16x32_bf16(x0, B1[0][0], a00, 0, 0, 0);
        a01 = __builtin_amdgcn_mfma_f32_16x16x32_bf16(x0, B1[0][1], a01, 0, 0, 0);
        a10 = __builtin_amdgcn_mfma_f32_16x16x32_bf16(x1, B1[0][0], a10, 0, 0, 0);
        a11 = __builtin_amdgcn_mfma_f32_16x16x32_bf16(x1, B1[0][1], a11, 0, 0, 0);
        a00 = __builtin_amdgcn_mfma_f32_16x16x32_bf16(x2, B1[1][0], a00, 0, 0, 0);
        a01 = __builtin_amdgcn_mfma_f32_16x16x32_bf16(x2, B1[1][1], a01, 0, 0, 0);
        a10 = __builtin_amdgcn_mfma_f32_16x16x32_bf16(x3, B1[1][0], a10, 0, 0, 0);
        a11 = __builtin_amdgcn_mfma_f32_16x16x32_bf16(x3, B1[1][1], a11, 0, 0, 0);
      }
    } else {
      // ONE sticky wait for all of this wave's producers (before any issue,
      // so the poll's compiler vmcnt(0) can't drain the load pipeline)
      {
        const unsigned tgt = (unsigned)t;
        bool pend = p1needA || p1needB;
        for (;;) {
          if (pend && ald32(p1fp) >= tgt) pend = false;
          if (__ballot(pend) == 0ull) break;
        }
      }
      if (chunk < 2) {
        // prevv from input (plain load, drained by compiler before use)
        prevv = *(const f32x4*)(inp + ((size_t)t * NB + mrow) * 64 + c0);
        // all 32 loads in flight; thresholds = loads remaining after block
        P1ISSUE(0, xa); P1ISSUE(1, xb); P1ISSUE(2, xc); P1ISSUE(3, xd);
        VMW(24); P1MFMA(0, xa);
        VMW(16); P1MFMA(1, xb);
        VMW(8);  P1MFMA(2, xc);
        VMW(0);  P1MFMA(3, xd);
      } else {
        P1ISSUE(0, xa); P1ISSUE(1, xb); P1ISSUE(2, xc); P1ISSUE(3, xd);
        // hoisted epilogue prev (producer chunk-2 covered by lane-16 wait);
        // issued LAST -> +1 on every threshold; consumed after phase-2 VMW(0)
        LLCLD(prevv, (SfOld + toff - 8192));
        VMW(25); P1MFMA(0, xa);
        VMW(17); P1MFMA(1, xb);
        VMW(9);  P1MFMA(2, xc);
        VMW(1);  P1MFMA(3, xd);
      }
    }
#pragma unroll
    for (int r = 0; r < 4; ++r) {            // ridx = mt*8 + nt*4 + r
      red[wave][r][lane]      = a00[r];
      red[wave][4 + r][lane]  = a01[r];
      red[wave][8 + r][lane]  = a10[r];
      red[wave][12 + r][lane] = a11[r];
    }
    __syncthreads();
    {
      short4v hv;
#pragma unroll
      for (int j = 0; j < 4; ++j) {
        const int nn   = nl + j;
        const int lidx = ((ml >> 2) & 3) * 16 + (nn & 15);   // C layout: lane=(row>>2)*16+col
        const int ridx = (ml >> 4) * 8 + (nn >> 4) * 4 + (ml & 3);
        float s = red[0][ridx][lidx] + red[1][ridx][lidx]
                + red[2][ridx][lidx] + red[3][ridx][lidx];
        s += b1r[j];
        hv[j] = f2bf(fabsf(s));
      }
      union { short4v s; u64 u; } hu; hu.s = hv;
      ast64(hb + toff, hu.u);   // tiled h store: wave-contiguous 512B
    }
    __syncthreads();   // all 4 waves' h stores drained (vmcnt0) before signal
    if (tid == 0)
      __hip_atomic_store(hgen + chunk * 16, (unsigned)t + 1,
                         __ATOMIC_RELAXED, __HIP_MEMORY_SCOPE_AGENT);

    // ================= phase 2: g = h @ W2^T ; state update =================
    f32x4 c00{}, c01{}, c10{}, c11{};
    {
      {  // one sticky wait for this wave's 16 h-producers
        const unsigned tgt = (unsigned)t + 1;
        bool pend = (lane < 16);
        for (;;) {
          if (pend && ald32(p2fp) >= tgt) pend = false;
          if (__ballot(pend) == 0ull) break;
        }
      }
      // all 32 loads in flight; drain by remaining-after-block counts
      P2ISSUE(0, xa); P2ISSUE(1, xb); P2ISSUE(2, xc); P2ISSUE(3, xd);
      VMW(24); P2MFMA(0, xa);
      VMW(16); P2MFMA(1, xb);
      VMW(8);  P2MFMA(2, xc);
      VMW(0);  P2MFMA(3, xd);
    }
#pragma unroll
    for (int r = 0; r < 4; ++r) {
      red[wave][r][lane]      = c00[r];
      red[wave][4 + r][lane]  = c01[r];
      red[wave][8 + r][lane]  = c10[r];
      red[wave][12 + r][lane] = c11[r];
    }
    __syncthreads();
    if (t < NSTEPS - 1) {
      if (n0 < SS) {   // cols >= SS are dropped by the shift (except final step)
        f32x4 gv;
#pragma unroll
        for (int j = 0; j < 4; ++j) {
          const int nn   = nl + j;
          const int lidx = ((ml >> 2) & 3) * 16 + (nn & 15);
          const int ridx = (ml >> 4) * 8 + (nn >> 4) * 4 + (ml & 3);
          gv[j] = red[0][ridx][lidx] + red[1][ridx][lidx]
                + red[2][ridx][lidx] + red[3][ridx][lidx] + b2r[j];
        }
        f32x4 sv; short4v sb;
#pragma unroll
        for (int j = 0; j < 4; ++j) {
          float vv = 0.9f * prevv[j] + 0.1f * gv[j];
          sv[j] = vv; sb[j] = f2bf(vv);
        }
        union { f32x4 f; u64 u[2]; } sfu; sfu.f = sv;
        float* pf = SfNew + toff;          // tiled Sf store (wave-contiguous 1KB)
        ast64(pf, sfu.u[0]);
        ast64(pf + 2, sfu.u[1]);
        union { short4v s; u64 u; } sbu; sbu.s = sb;
        ast64(SbNew + toff, sbu.u);        // tiled Sb store (wave-contiguous 512B)
      }
      __syncthreads();   // all 4 waves' S stores drained before signal
      if (tid == 0 && chunk < 62)
        __hip_atomic_store(sgen + chunk * 16, (unsigned)t + 1,
                           __ATOMIC_RELAXED, __HIP_MEMORY_SCOPE_AGENT);
    } else {
      // final step: out[m, :] = 0.9*s_in[m, 1984+o] + 0.1*(g+b2)[m, 1984+o]
      if (n0 >= SS) {
        f32x4 gv;
#pragma unroll
        for (int j = 0; j < 4; ++j) {
          const int nn   = nl + j;
          const int lidx = ((ml >> 2) & 3) * 16 + (nn & 15);
          const int ridx = (ml >> 4) * 8 + (nn >> 4) * 4 + (ml & 3);
          gv[j] = red[0][ridx][lidx] + red[1][ridx][lidx]
                + red[2][ridx][lidx] + red[3][ridx][lidx] + b2r[j];
        }
        f32x4 ov;
#pragma unroll
        for (int j = 0; j < 4; ++j) ov[j] = 0.9f * prevv[j] + 0.1f * gv[j];
        *(f32x4*)(out + (size_t)mrow * 64 + (c0 - SS)) = ov;
      }
    }
  }
}

extern "C" void kernel_launch(void* const* d_in, const int* in_sizes, int n_in,
                              void* d_out, int out_size, void* d_ws, size_t ws_size,
                              hipStream_t stream)
{
  (void)in_sizes; (void)n_in; (void)out_size; (void)ws_size;
  const float* inp = (const float*)d_in[0];
  const float* W1  = (const float*)d_in[1];
  const float* b1  = (const float*)d_in[2];
  const float* W2  = (const float*)d_in[3];
  const float* b2  = (const float*)d_in[4];
  float* out = (float*)d_out;

  // zero the flag area (ws is re-poisoned to 0xAA before every timed launch)
  hipMemsetAsync(d_ws, 0, 32768, stream);
  resrnn_kernel<<<dim3(256), dim3(256), 0, stream>>>(
      inp, W1, b1, W2, b2, out, (unsigned char*)d_ws);
}